// Round 4
// baseline (115.393 us; speedup 1.0000x reference)
//
#include <hip/hip_runtime.h>

#define NIN 64
#define NOUT 64
#define NTO 16
#define HH 192
#define WW 192
#define HO 190
#define WO 190
#define NBLK 2304            // 36 groups (9 tiles x 4 batch) x 64 out channels

__global__ __launch_bounds__(256, 6) void scm_kernel(
    const float* __restrict__ x,
    const float* __restrict__ w,
    const float* __restrict__ bias,
    const int* __restrict__ conn_in,
    float* __restrict__ out)
{
    const int tid = threadIdx.x;
    const int tx = tid & 15;        // col group of 4
    const int ty = tid >> 4;        // row group of 4

    // XCD-aware swizzle (bijective, 2304 % 8 == 0): o-minor so the 64 blocks
    // sharing one x-tile region land contiguously on one XCD's L2.
    const int lid = (blockIdx.x & 7) * (NBLK / 8) + (blockIdx.x >> 3);
    const int o   = lid & 63;
    const int g   = lid >> 6;       // 0..35
    const int tile = g % 9;
    const int b    = g / 9;
    const int tilex = tile % 3;
    const int tiley = tile / 3;
    const int i0 = tiley * 64;
    const int j0 = tilex * 64;

    // Channel-independent per-thread byte offsets for the 6 patch rows.
    // Row clamp <=191: clamped rows only feed outputs >=190 (discarded).
    // float2 col clamp <=190: substituted values only feed p>=2 taps of
    // edge columns >=190 (discarded).
    const int c0 = j0 + tx * 4;                 // float4 base col (16B aligned)
    const int c2 = (c0 + 4 > 190) ? 190 : c0 + 4; // float2 col (8B aligned)
    int off4[6], off2[6];
    #pragma unroll
    for (int r = 0; r < 6; ++r) {
        int gr = i0 + ty * 4 + r; if (gr > 191) gr = 191;
        off4[r] = (gr * WW + c0) * 4;
        off2[r] = (gr * WW + c2) * 4;
    }

    const char* xb = (const char*)x + (size_t)b * NIN * HH * WW * 4;
    const int kbase = o * NTO;

    float acc[4][4];
    #pragma unroll
    for (int i = 0; i < 4; ++i)
        #pragma unroll
        for (int p = 0; p < 4; ++p) acc[i][p] = 0.f;

    #pragma unroll 1
    for (int t = 0; t < NTO; ++t) {
        const int ci = __builtin_amdgcn_readfirstlane(conn_in[kbase + t]);
        const char* xc = xb + (size_t)ci * (HH * WW * 4);

        float wv[9];
        #pragma unroll
        for (int q = 0; q < 9; ++q) wv[q] = w[(kbase + t) * 9 + q];

        #pragma unroll
        for (int r = 0; r < 6; ++r) {
            const float4 v4 = *(const float4*)(xc + off4[r]);
            const float2 v2 = *(const float2*)(xc + off2[r]);
            const float rowv[6] = {v4.x, v4.y, v4.z, v4.w, v2.x, v2.y};
            #pragma unroll
            for (int i = 0; i < 4; ++i) {
                const int kh = r - i;
                if (kh >= 0 && kh < 3) {
                    #pragma unroll
                    for (int kw = 0; kw < 3; ++kw) {
                        const float wk = wv[kh * 3 + kw];
                        #pragma unroll
                        for (int p = 0; p < 4; ++p)
                            acc[i][p] = fmaf(wk, rowv[p + kw], acc[i][p]);
                    }
                }
            }
        }
    }

    const float bv = bias[o];
    float* outp = out + (size_t)(b * NOUT + o) * (HO * WO);
    #pragma unroll
    for (int i = 0; i < 4; ++i) {
        const int gi = i0 + ty * 4 + i;
        if (gi < HO) {
            const int gj = j0 + tx * 4;
            float* row = outp + (size_t)gi * WO + gj;
            if (gj + 3 < WO) {
                *(float2*)(row)     = make_float2(acc[i][0] + bv, acc[i][1] + bv);
                *(float2*)(row + 2) = make_float2(acc[i][2] + bv, acc[i][3] + bv);
            } else {
                #pragma unroll
                for (int p = 0; p < 4; ++p)
                    if (gj + p < WO) row[p] = acc[i][p] + bv;
            }
        }
    }
}

extern "C" void kernel_launch(void* const* d_in, const int* in_sizes, int n_in,
                              void* d_out, int out_size, void* d_ws, size_t ws_size,
                              hipStream_t stream) {
    const float* x       = (const float*)d_in[0];
    const float* weight  = (const float*)d_in[1];
    const float* bias    = (const float*)d_in[2];
    const int*   conn_in = (const int*)d_in[3];
    // d_in[4] = conn_out (implicit: k -> k/16)

    dim3 grid(NBLK);
    dim3 block(256);
    scm_kernel<<<grid, block, 0, stream>>>(x, weight, bias, conn_in, (float*)d_out);
}

// Round 5
// 89.042 us; speedup vs baseline: 1.2959x; 1.2959x over previous
//
#include <hip/hip_runtime.h>

#define NIN 64
#define NOUT 64
#define NTO 16
#define HH 192
#define WW 192
#define HO 190
#define WO 190
#define BUF_BYTES 20480      // 5 rounds * 256 lanes * 16B; real data = 66*17 units = 17952B
#define NBLK 2304            // 36 groups (9 tiles x 4 batch) x 64 out channels

typedef const __attribute__((address_space(1))) void gv_t;
typedef __attribute__((address_space(3))) void lv_t;

__global__ __launch_bounds__(256, 4) void scm_kernel(
    const float* __restrict__ x,
    const float* __restrict__ w,
    const float* __restrict__ bias,
    const int* __restrict__ conn_in,
    float* __restrict__ out)
{
    __shared__ char smem[2 * BUF_BYTES];

    const int tid = threadIdx.x;
    const int tx = tid & 15;        // col group of 4
    const int ty = tid >> 4;        // row group of 4

    // XCD-aware swizzle (bijective, 2304 % 8 == 0), o-minor for L2 gather reuse.
    const int lid = (blockIdx.x & 7) * (NBLK / 8) + (blockIdx.x >> 3);
    const int o   = lid & 63;
    const int g   = lid >> 6;       // 0..35
    const int tile = g % 9;
    const int b    = g / 9;
    const int i0 = (tile / 3) * 64;
    const int j0 = (tile % 3) * 64;

    // ---- LDS layout: 66 rows x 17 units(16B). Physical unit for logical
    // (row, c) = row*17 + (c+row)%17  (mod-17 rotation, bank-conflict killer).
    // global_load_lds writes linearly, so the SOURCE is pre-permuted (m173):
    // physical unit u = s*256+tid holds logical c = (u%17 - row%17) mod 17.
    int goff[5];
    #pragma unroll
    for (int s = 0; s < 5; ++s) {
        int u = s * 256 + tid;
        int row = u / 17;
        int cu = u - row * 17;
        int rm = row - (row / 17) * 17;
        int c = cu - rm; if (c < 0) c += 17;
        int gr = i0 + row; if (gr > 191) gr = 191;   // clamped slots feed only discarded outputs
        int gc = j0 + c * 4; if (gc > 188) gc = 188; // keep 16B within the image row
        goff[s] = (gr * WW + gc) * 4;
    }

    // Read offsets (channel-independent, 16B units, same rotation):
    // A = float4 (cols tx*4..+3) at unit row*17+(tx+row)%17
    // B = float2 (cols (tx+1)*4, +1) = first 8B of unit row*17+(tx+1+row)%17
    int offA[6], offB[6];
    #pragma unroll
    for (int r = 0; r < 6; ++r) {
        int row = ty * 4 + r;
        int rm = row - (row / 17) * 17;
        int a  = tx + rm;     if (a  >= 17) a  -= 17;
        int bu = tx + 1 + rm; if (bu >= 17) bu -= 17;
        offA[r] = (row * 17 + a) * 16;
        offB[r] = (row * 17 + bu) * 16;
    }

    const int wid = __builtin_amdgcn_readfirstlane(tid >> 6);
    const char* xb = (const char*)x + (size_t)b * NIN * HH * WW * 4;
    char* lwave = smem + wid * 1024;
    const int kbase = o * NTO;

#define STAGE(ci, buf) do {                                                     \
        const char* _src = xb + (size_t)(ci) * (HH * WW * 4);                   \
        char* _lb = lwave + (buf) * BUF_BYTES;                                  \
        _Pragma("unroll")                                                       \
        for (int _s = 0; _s < 5; ++_s)                                          \
            __builtin_amdgcn_global_load_lds((gv_t*)(_src + goff[_s]),          \
                                             (lv_t*)(_lb + _s * 4096),          \
                                             16, 0, 0);                         \
    } while (0)

    float acc[4][4];
    #pragma unroll
    for (int i = 0; i < 4; ++i)
        #pragma unroll
        for (int p = 0; p < 4; ++p) acc[i][p] = 0.f;

    // prologue: stage channel 0
    {
        const int c0 = __builtin_amdgcn_readfirstlane(conn_in[kbase]);
        STAGE(c0, 0);
    }

    #pragma unroll 1
    for (int t = 0; t < NTO; ++t) {
        const int cur = t & 1;
        if (t < NTO - 1) {
            const int cn = __builtin_amdgcn_readfirstlane(conn_in[kbase + t + 1]);
            STAGE(cn, cur ^ 1);
        }
        float wv[9];
        #pragma unroll
        for (int q = 0; q < 9; ++q) wv[q] = w[(kbase + t) * 9 + q];

        // wait for THIS channel's 5 loads only; keep next channel's 5 in flight
        if (t < NTO - 1) asm volatile("s_waitcnt vmcnt(5)" ::: "memory");
        else             asm volatile("s_waitcnt vmcnt(0)" ::: "memory");
        __builtin_amdgcn_s_barrier();

        const char* rb = smem + cur * BUF_BYTES;
        #pragma unroll
        for (int r = 0; r < 6; ++r) {
            const float4 v4 = *(const float4*)(rb + offA[r]);
            const float2 v2 = *(const float2*)(rb + offB[r]);
            const float rowv[6] = {v4.x, v4.y, v4.z, v4.w, v2.x, v2.y};
            #pragma unroll
            for (int i = 0; i < 4; ++i) {
                const int kh = r - i;
                if (kh >= 0 && kh < 3) {
                    #pragma unroll
                    for (int kw = 0; kw < 3; ++kw) {
                        const float wk = wv[kh * 3 + kw];
                        #pragma unroll
                        for (int p = 0; p < 4; ++p)
                            acc[i][p] = fmaf(wk, rowv[p + kw], acc[i][p]);
                    }
                }
            }
        }
        // our ds_reads must be done before anyone restages this buffer
        asm volatile("s_waitcnt lgkmcnt(0)" ::: "memory");
        if (t < NTO - 1) __builtin_amdgcn_s_barrier();
    }
#undef STAGE

    const float bv = bias[o];
    float* outp = out + (size_t)(b * NOUT + o) * (HO * WO);
    #pragma unroll
    for (int i = 0; i < 4; ++i) {
        const int gi = i0 + ty * 4 + i;
        if (gi < HO) {
            const int gj = j0 + tx * 4;
            float* row = outp + (size_t)gi * WO + gj;
            if (gj + 3 < WO) {
                *(float2*)(row)     = make_float2(acc[i][0] + bv, acc[i][1] + bv);
                *(float2*)(row + 2) = make_float2(acc[i][2] + bv, acc[i][3] + bv);
            } else {
                #pragma unroll
                for (int p = 0; p < 4; ++p)
                    if (gj + p < WO) row[p] = acc[i][p] + bv;
            }
        }
    }
}

extern "C" void kernel_launch(void* const* d_in, const int* in_sizes, int n_in,
                              void* d_out, int out_size, void* d_ws, size_t ws_size,
                              hipStream_t stream) {
    const float* x       = (const float*)d_in[0];
    const float* weight  = (const float*)d_in[1];
    const float* bias    = (const float*)d_in[2];
    const int*   conn_in = (const int*)d_in[3];
    // d_in[4] = conn_out (implicit: k -> k/16)

    dim3 grid(NBLK);
    dim3 block(256);
    scm_kernel<<<grid, block, 0, stream>>>(x, weight, bias, conn_in, (float*)d_out);
}